// Round 8
// baseline (254.033 us; speedup 1.0000x reference)
//
#include <hip/hip_runtime.h>
#include <math.h>

// Problem constants: B=4, N=4096, C=2048, E=64, K=2
#define T_TOKENS 16384
#define C_DIM    2048
#define N_SEQ    4096
#define E_EXP    64
#define GN       131072   // gate elements per split part (64*2048)
#define FBLK     512      // fused kernel blocks (32 tokens each)

typedef __attribute__((ext_vector_type(8))) short  short8;   // 8 bf16 = 4 VGPR
typedef __attribute__((ext_vector_type(4))) float  floatx4;

// ---- exact 3-way bf16 decomposition (truncation; residuals exact) ----------
__device__ __forceinline__ void splitv(float v, ushort& h, ushort& m, ushort& l) {
    unsigned u = __float_as_uint(v);
    h = (ushort)(u >> 16);
    float f1 = v - __uint_as_float(u & 0xffff0000u);       // exact
    unsigned u1 = __float_as_uint(f1);
    m = (ushort)(u1 >> 16);
    float f2 = f1 - __uint_as_float(u1 & 0xffff0000u);     // exact
    l = (ushort)(__float_as_uint(f2) >> 16);
}

__device__ __forceinline__ void splitpack8(const float4& a, const float4& b,
                                           short8& h, short8& m, short8& l) {
    ushort hh, mm, ll;
    splitv(a.x, hh, mm, ll); h[0] = hh; m[0] = mm; l[0] = ll;
    splitv(a.y, hh, mm, ll); h[1] = hh; m[1] = mm; l[1] = ll;
    splitv(a.z, hh, mm, ll); h[2] = hh; m[2] = mm; l[2] = ll;
    splitv(a.w, hh, mm, ll); h[3] = hh; m[3] = mm; l[3] = ll;
    splitv(b.x, hh, mm, ll); h[4] = hh; m[4] = mm; l[4] = ll;
    splitv(b.y, hh, mm, ll); h[5] = hh; m[5] = mm; l[5] = ll;
    splitv(b.z, hh, mm, ll); h[6] = hh; m[6] = mm; l[6] = ll;
    splitv(b.w, hh, mm, ll); h[7] = hh; m[7] = mm; l[7] = ll;
}

// RNE split for the one-time gate_w preprocessing
__device__ __forceinline__ void split3rne(float v, ushort& h, ushort& m, ushort& l) {
    unsigned u = __float_as_uint(v);
    unsigned r = (u + 0x7fffu + ((u >> 16) & 1u)) >> 16;
    h = (ushort)r;
    float e1 = v - __uint_as_float(r << 16);
    u = __float_as_uint(e1);
    r = (u + 0x7fffu + ((u >> 16) & 1u)) >> 16;
    m = (ushort)r;
    float e2 = e1 - __uint_as_float(r << 16);
    l = (ushort)(__float_as_uint(e2) >> 16);
}

// ---- shared ctx body: wave computes ctx[0..3][j] (bit-identical to R0) ----
__device__ __forceinline__ void ctx_body(
    int j, int lane, const float* __restrict__ rc,
    const float* __restrict__ ctx_w, float* __restrict__ ctx_out)
{
    const float4* wr = (const float4*)(ctx_w + (size_t)j * C_DIM);
    const float4* r0 = (const float4*)(rc);
    const float4* r1 = (const float4*)(rc + C_DIM);
    const float4* r2 = (const float4*)(rc + 2 * C_DIM);
    const float4* r3 = (const float4*)(rc + 3 * C_DIM);

    float s0 = 0.f, s1 = 0.f, s2 = 0.f, s3 = 0.f;
#pragma unroll
    for (int it = 0; it < 8; ++it) {
        float4 a  = wr[it * 64 + lane];
        float4 c0 = r0[it * 64 + lane];
        float4 c1 = r1[it * 64 + lane];
        float4 c2 = r2[it * 64 + lane];
        float4 c3 = r3[it * 64 + lane];
        s0 += a.x * c0.x + a.y * c0.y + a.z * c0.z + a.w * c0.w;
        s1 += a.x * c1.x + a.y * c1.y + a.z * c1.z + a.w * c1.w;
        s2 += a.x * c2.x + a.y * c2.y + a.z * c2.z + a.w * c2.w;
        s3 += a.x * c3.x + a.y * c3.y + a.z * c3.z + a.w * c3.w;
    }
#pragma unroll
    for (int off = 32; off; off >>= 1) {
        s0 += __shfl_xor(s0, off, 64);
        s1 += __shfl_xor(s1, off, 64);
        s2 += __shfl_xor(s2, off, 64);
        s3 += __shfl_xor(s3, off, 64);
    }
    if (lane == 0) {
        ctx_out[j]             = s0;
        ctx_out[C_DIM + j]     = s1;
        ctx_out[2 * C_DIM + j] = s2;
        ctx_out[3 * C_DIM + j] = s3;
    }
}

// ---------------------------------------------------------------------------
// Kernel 1 (R4-proven): 512 blocks. All blocks do the gsp split (one element
// per thread, 512*256 = GN); each wave computes ctx[0..3][j] for one j.
// ---------------------------------------------------------------------------
__global__ __launch_bounds__(256) void pre_kernel(
    const float* __restrict__ rc, const float* __restrict__ ctx_w,
    const float* __restrict__ gw, float* __restrict__ ctx_out,
    ushort* __restrict__ gsp)
{
    if (gsp != nullptr) {
        const int idx  = blockIdx.x * 256 + threadIdx.x;   // 0..131071
        const int j    = idx & 7;
        const int e    = (idx >> 3) & 63;
        const int koct = idx >> 9;
        float g = gw[(size_t)e * C_DIM + koct * 8 + j];
        ushort h, m, l;
        split3rne(g, h, m, l);
        gsp[idx]          = h;
        gsp[GN + idx]     = m;
        gsp[2 * GN + idx] = l;
    }
    const int lane = threadIdx.x & 63;
    const int j    = blockIdx.x * 4 + (threadIdx.x >> 6);
    ctx_body(j, lane, rc, ctx_w, ctx_out);
}

// ---------------------------------------------------------------------------
// Kernel 2: cl[b][e] = dot(ctx[b,:], gate_w[e,:]) — 64 blocks, tiny.
// ---------------------------------------------------------------------------
__global__ __launch_bounds__(256) void cl_kernel(
    const float* __restrict__ gw, const float* __restrict__ ctx,
    float* __restrict__ cl)
{
    const int lane = threadIdx.x & 63;
    const int pk   = blockIdx.x * 4 + (threadIdx.x >> 6);  // 0..255
    const int b    = pk >> 6;
    const int e    = pk & 63;
    const float4* wr = (const float4*)(gw + (size_t)e * C_DIM);
    const float4* cr = (const float4*)(ctx + (size_t)b * C_DIM);
    float s = 0.f;
#pragma unroll
    for (int it = 0; it < 8; ++it) {
        float4 a = wr[it * 64 + lane];
        float4 c = cr[it * 64 + lane];
        s += a.x * c.x + a.y * c.y + a.z * c.z + a.w * c.w;
    }
#pragma unroll
    for (int off = 32; off; off >>= 1) s += __shfl_xor(s, off, 64);
    if (lane == 0) cl[pk] = s;
}

// ---------------------------------------------------------------------------
// Kernel 3 (R8): K-FULL fused GEMM + in-register epilogue.
// Mechanism: split-K read x as 128B chunks at 8KB stride interleaved across
// the whole chip -> HBM row-buffer thrashing at ~1.2 TB/s (R2 counters: all
// pipes idle, 1.2 TB/s on 104 MB = the whole 85us). All scheduling fixes
// (R3-R7) were null because none changed DRAM locality. Here each wave owns
// 16 token rows and sweeps K=0..2048 SEQUENTIALLY: per row, consecutive
// K-steps read consecutive 128B -> long per-row bursts, row-buffer hits.
// 512 blocks x 2 waves (1024 waves, 4/CU, even across XCDs). A 2-deep
// register prefetch; B in-step from L2 (gsp 786KB is L2-resident).
// Epilogue fused: lane holds expert e=16nt+l15 of token quad*4+r; top-2 +
// sumexp via local-4 + 16-lane butterfly (same comparator as proven code);
// eliminates P (34MB traffic) and the epilogue dispatch entirely.
// ---------------------------------------------------------------------------
__global__ __launch_bounds__(128, 1) void fused_kernel(
    const float* __restrict__ x, const ushort* __restrict__ gsp,
    const float* __restrict__ cl, float* __restrict__ out,
    float* __restrict__ bp)
{
    __shared__ float red[2][128];

    const int tid  = threadIdx.x;
    const int wv   = tid >> 6;              // 0..1
    const int lane = tid & 63;
    const int l15  = lane & 15;
    const int quad = lane >> 4;
    const int t0   = blockIdx.x * 32;       // 32 tokens per block
    const int b    = t0 >> 12;              // batch (4096 tokens each)

    floatx4 acc[4];
#pragma unroll
    for (int nt = 0; nt < 4; ++nt) acc[nt] = (floatx4){0.f, 0.f, 0.f, 0.f};

    // A stream: lane (l15,quad) reads row t0+wv*16+l15, 8 floats at quad*8,
    // advancing 32 floats per K-step -> sequential 128B bursts per row.
    const float* xr = x + (size_t)(t0 + wv * 16 + l15) * C_DIM + quad * 8;

    // ---- prologue: A for ks=0 and ks=1 ----
    float4 a00 = *(const float4*)(xr);
    float4 a01 = *(const float4*)(xr + 4);
    float4 n00 = *(const float4*)(xr + 32);
    float4 n01 = *(const float4*)(xr + 36);

#pragma unroll 2
    for (int ks = 0; ks < 64; ++ks) {
        // --- issue A[ks+2] (wrap on tail; discarded) ---
        const int fk = (ks + 2 < 64) ? ks + 2 : 0;
        float4 f00 = *(const float4*)(xr + fk * 32);
        float4 f01 = *(const float4*)(xr + fk * 32 + 4);

        // --- B fragments for this K-step (L2-resident gsp) ---
        const ushort* bks = gsp + ((size_t)(ks * 4 + quad) * 64 + l15) * 8;
        short8 bh[4], bm[4], bl[4];
#pragma unroll
        for (int nt = 0; nt < 4; ++nt) {
            const ushort* bp_ = bks + (size_t)(16 * nt) * 8;
            bh[nt] = *(const short8*)(bp_);
            bm[nt] = *(const short8*)(bp_ + GN);
            bl[nt] = *(const short8*)(bp_ + 2 * (size_t)GN);
        }

        // --- split current A ---
        short8 ah, am, al;
        splitpack8(a00, a01, ah, am, al);

#pragma unroll
        for (int nt = 0; nt < 4; ++nt) {
            acc[nt] = __builtin_amdgcn_mfma_f32_16x16x32_bf16(ah, bh[nt], acc[nt], 0, 0, 0);
            acc[nt] = __builtin_amdgcn_mfma_f32_16x16x32_bf16(ah, bm[nt], acc[nt], 0, 0, 0);
            acc[nt] = __builtin_amdgcn_mfma_f32_16x16x32_bf16(am, bh[nt], acc[nt], 0, 0, 0);
            acc[nt] = __builtin_amdgcn_mfma_f32_16x16x32_bf16(ah, bl[nt], acc[nt], 0, 0, 0);
            acc[nt] = __builtin_amdgcn_mfma_f32_16x16x32_bf16(al, bh[nt], acc[nt], 0, 0, 0);
            acc[nt] = __builtin_amdgcn_mfma_f32_16x16x32_bf16(am, bm[nt], acc[nt], 0, 0, 0);
        }

        a00 = n00; a01 = n01; n00 = f00; n01 = f01;
    }

    // ---- fused epilogue ----
    // D layout (verified): token row = quad*4 + r, expert col = 16*nt + l15.
    float clv[4];
#pragma unroll
    for (int nt = 0; nt < 4; ++nt) clv[nt] = cl[b * 64 + 16 * nt + l15];

    float imp4[4] = {0.f, 0.f, 0.f, 0.f};
    float cnt4[4] = {0.f, 0.f, 0.f, 0.f};

#pragma unroll
    for (int r = 0; r < 4; ++r) {
        const int t = t0 + wv * 16 + quad * 4 + r;
        float v[4], p[4];
#pragma unroll
        for (int nt = 0; nt < 4; ++nt) {
            v[nt] = acc[nt][r] + clv[nt];
            p[nt] = expf(v[nt]);
        }
        float s = (p[0] + p[1]) + (p[2] + p[3]);

        // local top-2 over the lane's 4 experts (ids 16nt+l15, increasing)
        float v1 = v[0];      int i1 = l15;
        float v2 = -INFINITY; int i2 = 0x7fffffff;
#pragma unroll
        for (int k = 1; k < 4; ++k) {
            const int e = 16 * k + l15;
            if (v[k] > v1) { v2 = v1; i2 = i1; v1 = v[k]; i1 = e; }
            else if (v[k] > v2 || (v[k] == v2 && e < i2)) { v2 = v[k]; i2 = e; }
        }

        // 16-lane butterfly merge (same comparator as proven epilogue)
#pragma unroll
        for (int off = 8; off; off >>= 1) {
            float ov1 = __shfl_xor(v1, off, 64);
            int   oi1 = __shfl_xor(i1, off, 64);
            float ov2 = __shfl_xor(v2, off, 64);
            int   oi2 = __shfl_xor(i2, off, 64);
            s += __shfl_xor(s, off, 64);
            const bool aw = (ov1 < v1) || (ov1 == v1 && i1 < oi1);
            const float lv = aw ? ov1 : v1;  const int li = aw ? oi1 : i1;
            const float wv2 = aw ? v2 : ov2; const int wi = aw ? i2 : oi2;
            if (!aw) { v1 = ov1; i1 = oi1; }
            const bool sw = (wv2 < lv) || (wv2 == lv && li < wi);
            v2 = sw ? lv : wv2; i2 = sw ? li : wi;
        }

#pragma unroll
        for (int nt = 0; nt < 4; ++nt) {
            const int e = 16 * nt + l15;
            imp4[nt] += p[nt] / s;
            cnt4[nt] += ((e == i1) ? 1.f : 0.f) + ((e == i2) ? 1.f : 0.f);
        }

        if (l15 == 0) {
            const float e2 = expf(v2 - v1);
            out[2 * t]     = (float)i1;
            out[2 * t + 1] = (float)i2;
            out[2 * T_TOKENS + 2 * t]     = 1.f / (1.f + e2);
            out[2 * T_TOKENS + 2 * t + 1] = e2 / (1.f + e2);
        }
    }

    // reduce imp/cnt across the 4 quads (lanes sharing the same expert set)
#pragma unroll
    for (int nt = 0; nt < 4; ++nt) {
        imp4[nt] += __shfl_xor(imp4[nt], 16, 64);
        imp4[nt] += __shfl_xor(imp4[nt], 32, 64);
        cnt4[nt] += __shfl_xor(cnt4[nt], 16, 64);
        cnt4[nt] += __shfl_xor(cnt4[nt], 32, 64);
    }
    if (quad == 0) {
#pragma unroll
        for (int nt = 0; nt < 4; ++nt) {
            red[wv][16 * nt + l15]      = imp4[nt];
            red[wv][64 + 16 * nt + l15] = cnt4[nt];
        }
    }
    __syncthreads();
    if (tid < 128)
        bp[(size_t)blockIdx.x * 128 + tid] = red[0][tid] + red[1][tid];
}

// ---------------------------------------------------------------------------
// Kernel 4: parallel bp reduce -> aux loss (proven; nb = FBLK)
// ---------------------------------------------------------------------------
__global__ __launch_bounds__(1024) void aux_kernel(
    const float* __restrict__ bp, int nb, float* __restrict__ out_aux)
{
    __shared__ float4 red[32][32];
    const int tid = threadIdx.x;
    const int c4  = tid & 31;
    const int grp = tid >> 5;

    const float4* bp4 = (const float4*)bp;
    float4 s = make_float4(0.f, 0.f, 0.f, 0.f);
    for (int r = grp; r < nb; r += 32) {
        float4 v = bp4[(size_t)r * 32 + c4];
        s.x += v.x; s.y += v.y; s.z += v.z; s.w += v.w;
    }
    red[grp][c4] = s;
    __syncthreads();

    if (tid < 32) {
        float4 t = make_float4(0.f, 0.f, 0.f, 0.f);
#pragma unroll
        for (int g = 0; g < 32; ++g) {
            float4 v = red[g][tid];
            t.x += v.x; t.y += v.y; t.z += v.z; t.w += v.w;
        }
        red[0][tid] = t;
    }
    __syncthreads();

    if (tid < 16) {
        float4 a = red[0][tid];
        float4 b = red[0][tid + 16];
        float v = a.x * b.x + a.y * b.y + a.z * b.z + a.w * b.w;
#pragma unroll
        for (int off = 8; off; off >>= 1) v += __shfl_xor(v, off, 64);
        if (tid == 0)
            out_aux[0] = (float)E_EXP * v / ((float)T_TOKENS * (float)T_TOKENS);
    }
}

// ---------------------------------------------------------------------------
// Fallback path kernels (ws too small): fused fp32 + aux (proven)
// ---------------------------------------------------------------------------
#define TM    64
#define FKC   64
#define FLSTR 68
__global__ __launch_bounds__(256) void router_fused_kernel(
    const float* __restrict__ x, const float* __restrict__ gate_w,
    const float* __restrict__ ctx, float* __restrict__ out,
    float* __restrict__ bp)
{
    __shared__ float xs[TM][FLSTR];
    __shared__ float gs[E_EXP][FLSTR];
    __shared__ float ls[TM][FLSTR];
    __shared__ float red[4][128];

    const int tid = threadIdx.x;
    const int eg  = tid & 15;
    const int tg  = tid >> 4;
    const int t0  = blockIdx.x * TM;
    const int b   = t0 / N_SEQ;
    const int sr  = tid >> 4;
    const int scg = tid & 15;
    const float* ctx_row = ctx + (size_t)b * C_DIM;

    float4 acc[4][4];
#pragma unroll
    for (int i = 0; i < 4; ++i)
#pragma unroll
        for (int j = 0; j < 4; ++j) acc[i][j] = make_float4(0.f, 0.f, 0.f, 0.f);

    float4 px[4], pg[4], pc;
    auto prefetch = [&](int kc) {
        const int c0 = kc * FKC + scg * 4;
        pc = *(const float4*)(ctx_row + c0);
#pragma unroll
        for (int i = 0; i < 4; ++i) {
            px[i] = *(const float4*)(x + (size_t)(t0 + sr + 16 * i) * C_DIM + c0);
            pg[i] = *(const float4*)(gate_w + (size_t)(sr + 16 * i) * C_DIM + c0);
        }
    };

    prefetch(0);
    const int NCHUNK = C_DIM / FKC;
    for (int kc = 0; kc < NCHUNK; ++kc) {
        __syncthreads();
#pragma unroll
        for (int i = 0; i < 4; ++i) {
            float4 v = px[i];
            v.x += pc.x; v.y += pc.y; v.z += pc.z; v.w += pc.w;
            *(float4*)&xs[sr + 16 * i][scg * 4] = v;
            *(float4*)&gs[sr + 16 * i][scg * 4] = pg[i];
        }
        __syncthreads();
        if (kc + 1 < NCHUNK) prefetch(kc + 1);
#pragma unroll
        for (int cc = 0; cc < FKC; cc += 4) {
            float4 xv[4], gv[4];
#pragma unroll
            for (int i = 0; i < 4; ++i) xv[i] = *(const float4*)&xs[tg + 16 * i][cc];
#pragma unroll
            for (int j = 0; j < 4; ++j) gv[j] = *(const float4*)&gs[eg + 16 * j][cc];
#pragma unroll
            for (int i = 0; i < 4; ++i)
#pragma unroll
                for (int j = 0; j < 4; ++j) {
                    acc[i][j].x = fmaf(xv[i].x, gv[j].x, acc[i][j].x);
                    acc[i][j].y = fmaf(xv[i].y, gv[j].y, acc[i][j].y);
                    acc[i][j].z = fmaf(xv[i].z, gv[j].z, acc[i][j].z);
                    acc[i][j].w = fmaf(xv[i].w, gv[j].w, acc[i][j].w);
                }
        }
    }

    __syncthreads();
#pragma unroll
    for (int i = 0; i < 4; ++i)
#pragma unroll
        for (int j = 0; j < 4; ++j)
            ls[tg + 16 * i][eg + 16 * j] =
                (acc[i][j].x + acc[i][j].y) + (acc[i][j].z + acc[i][j].w);
    __syncthreads();

    const int wv   = tid >> 6;
    const int lane = tid & 63;
    float imp_acc = 0.f, cnt_acc = 0.f;

    for (int tt = 0; tt < 16; ++tt) {
        const int tokL = wv * 16 + tt;
        const float v = ls[tokL][lane];
        const float p = expf(v);
        float v1 = v;  int i1 = lane;
        float v2 = -INFINITY; int i2 = 0x7fffffff;
        float s = p;
#pragma unroll
        for (int off = 32; off; off >>= 1) {
            float ov1 = __shfl_xor(v1, off, 64);
            int   oi1 = __shfl_xor(i1, off, 64);
            float ov2 = __shfl_xor(v2, off, 64);
            int   oi2 = __shfl_xor(i2, off, 64);
            s += __shfl_xor(s, off, 64);
            const bool aw = (ov1 < v1) || (ov1 == v1 && i1 < oi1);
            const float lv = aw ? ov1 : v1;  const int li = aw ? oi1 : i1;
            const float wv2 = aw ? v2 : ov2; const int wi = aw ? i2 : oi2;
            if (!aw) { v1 = ov1; i1 = oi1; }
            const bool sw = (wv2 < lv) || (wv2 == lv && li < wi);
            v2 = sw ? lv : wv2; i2 = sw ? li : wi;
        }
        imp_acc += p / s;
        if (lane == i1 || lane == i2) cnt_acc += 1.f;
        if (lane == 0) {
            const int t = t0 + tokL;
            const float e2 = expf(v2 - v1);
            out[2 * t]     = (float)i1;
            out[2 * t + 1] = (float)i2;
            out[2 * T_TOKENS + 2 * t]     = 1.f / (1.f + e2);
            out[2 * T_TOKENS + 2 * t + 1] = e2 / (1.f + e2);
        }
    }

    red[wv][lane]      = imp_acc;
    red[wv][64 + lane] = cnt_acc;
    __syncthreads();
    if (tid < 128) {
        float s = red[0][tid] + red[1][tid] + red[2][tid] + red[3][tid];
        bp[(size_t)blockIdx.x * 128 + tid] = s;
    }
}

extern "C" void kernel_launch(void* const* d_in, const int* in_sizes, int n_in,
                              void* d_out, int out_size, void* d_ws, size_t ws_size,
                              hipStream_t stream)
{
    (void)in_sizes; (void)n_in; (void)out_size;
    const float* x      = (const float*)d_in[0];
    const float* rc     = (const float*)d_in[1];
    const float* gate_w = (const float*)d_in[2];
    const float* ctx_w  = (const float*)d_in[3];
    float* out = (float*)d_out;

    float*  ctx = (float*)d_ws;                            // 8192 f
    float*  cl  = ctx + 8192;                              // 256 f
    float*  bp  = cl + 256;                                // FBLK*128 f
    ushort* gsp = (ushort*)(bp + (size_t)FBLK * 128);      // 3*GN us

    const size_t need =
        (8192 + 256 + (size_t)FBLK * 128) * sizeof(float)
        + (size_t)3 * GN * sizeof(ushort);

    if (ws_size >= need) {
        pre_kernel<<<512, 256, 0, stream>>>(rc, ctx_w, gate_w, ctx, gsp);
        cl_kernel<<<64, 256, 0, stream>>>(gate_w, ctx, cl);
        fused_kernel<<<FBLK, 128, 0, stream>>>(x, gsp, cl, out, bp);
        aux_kernel<<<1, 1024, 0, stream>>>(bp, FBLK, out + 2 * 2 * T_TOKENS);
    } else {
        pre_kernel<<<512, 256, 0, stream>>>(rc, ctx_w, gate_w, ctx, nullptr);
        router_fused_kernel<<<256, 256, 0, stream>>>(x, gate_w, ctx, out, bp);
        aux_kernel<<<1, 1024, 0, stream>>>(bp, 256, out + 2 * 2 * T_TOKENS);
    }
}

// Round 9
// 242.247 us; speedup vs baseline: 1.0487x; 1.0487x over previous
//
#include <hip/hip_runtime.h>
#include <math.h>

// Problem constants: B=4, N=4096, C=2048, E=64, K=2
#define T_TOKENS 16384
#define C_DIM    2048
#define N_SEQ    4096
#define E_EXP    64
#define GN       131072   // gate elements per split part (64*2048)
#define FBLK     512      // fused kernel blocks (32 tokens each)

typedef __attribute__((ext_vector_type(8))) short  short8;   // 8 bf16 = 4 VGPR
typedef __attribute__((ext_vector_type(4))) float  floatx4;

// ---- exact 3-way bf16 decomposition (truncation; residuals exact) ----------
__device__ __forceinline__ void splitv(float v, ushort& h, ushort& m, ushort& l) {
    unsigned u = __float_as_uint(v);
    h = (ushort)(u >> 16);
    float f1 = v - __uint_as_float(u & 0xffff0000u);       // exact
    unsigned u1 = __float_as_uint(f1);
    m = (ushort)(u1 >> 16);
    float f2 = f1 - __uint_as_float(u1 & 0xffff0000u);     // exact
    l = (ushort)(__float_as_uint(f2) >> 16);
}

__device__ __forceinline__ void splitpack8(const float4& a, const float4& b,
                                           short8& h, short8& m, short8& l) {
    ushort hh, mm, ll;
    splitv(a.x, hh, mm, ll); h[0] = hh; m[0] = mm; l[0] = ll;
    splitv(a.y, hh, mm, ll); h[1] = hh; m[1] = mm; l[1] = ll;
    splitv(a.z, hh, mm, ll); h[2] = hh; m[2] = mm; l[2] = ll;
    splitv(a.w, hh, mm, ll); h[3] = hh; m[3] = mm; l[3] = ll;
    splitv(b.x, hh, mm, ll); h[4] = hh; m[4] = mm; l[4] = ll;
    splitv(b.y, hh, mm, ll); h[5] = hh; m[5] = mm; l[5] = ll;
    splitv(b.z, hh, mm, ll); h[6] = hh; m[6] = mm; l[6] = ll;
    splitv(b.w, hh, mm, ll); h[7] = hh; m[7] = mm; l[7] = ll;
}

// RNE split for the one-time gate_w preprocessing
__device__ __forceinline__ void split3rne(float v, ushort& h, ushort& m, ushort& l) {
    unsigned u = __float_as_uint(v);
    unsigned r = (u + 0x7fffu + ((u >> 16) & 1u)) >> 16;
    h = (ushort)r;
    float e1 = v - __uint_as_float(r << 16);
    u = __float_as_uint(e1);
    r = (u + 0x7fffu + ((u >> 16) & 1u)) >> 16;
    m = (ushort)r;
    float e2 = e1 - __uint_as_float(r << 16);
    l = (ushort)(__float_as_uint(e2) >> 16);
}

// ---- shared ctx body: wave computes ctx[0..3][j] (bit-identical to R0) ----
__device__ __forceinline__ void ctx_body(
    int j, int lane, const float* __restrict__ rc,
    const float* __restrict__ ctx_w, float* __restrict__ ctx_out)
{
    const float4* wr = (const float4*)(ctx_w + (size_t)j * C_DIM);
    const float4* r0 = (const float4*)(rc);
    const float4* r1 = (const float4*)(rc + C_DIM);
    const float4* r2 = (const float4*)(rc + 2 * C_DIM);
    const float4* r3 = (const float4*)(rc + 3 * C_DIM);

    float s0 = 0.f, s1 = 0.f, s2 = 0.f, s3 = 0.f;
#pragma unroll
    for (int it = 0; it < 8; ++it) {
        float4 a  = wr[it * 64 + lane];
        float4 c0 = r0[it * 64 + lane];
        float4 c1 = r1[it * 64 + lane];
        float4 c2 = r2[it * 64 + lane];
        float4 c3 = r3[it * 64 + lane];
        s0 += a.x * c0.x + a.y * c0.y + a.z * c0.z + a.w * c0.w;
        s1 += a.x * c1.x + a.y * c1.y + a.z * c1.z + a.w * c1.w;
        s2 += a.x * c2.x + a.y * c2.y + a.z * c2.z + a.w * c2.w;
        s3 += a.x * c3.x + a.y * c3.y + a.z * c3.z + a.w * c3.w;
    }
#pragma unroll
    for (int off = 32; off; off >>= 1) {
        s0 += __shfl_xor(s0, off, 64);
        s1 += __shfl_xor(s1, off, 64);
        s2 += __shfl_xor(s2, off, 64);
        s3 += __shfl_xor(s3, off, 64);
    }
    if (lane == 0) {
        ctx_out[j]             = s0;
        ctx_out[C_DIM + j]     = s1;
        ctx_out[2 * C_DIM + j] = s2;
        ctx_out[3 * C_DIM + j] = s3;
    }
}

// ---------------------------------------------------------------------------
// Kernel 1 (R4-proven): 512 blocks. All blocks do the gsp split; each wave
// computes ctx[0..3][j] for one j.
// ---------------------------------------------------------------------------
__global__ __launch_bounds__(256) void pre_kernel(
    const float* __restrict__ rc, const float* __restrict__ ctx_w,
    const float* __restrict__ gw, float* __restrict__ ctx_out,
    ushort* __restrict__ gsp)
{
    if (gsp != nullptr) {
        const int idx  = blockIdx.x * 256 + threadIdx.x;   // 0..131071
        const int j    = idx & 7;
        const int e    = (idx >> 3) & 63;
        const int koct = idx >> 9;
        float g = gw[(size_t)e * C_DIM + koct * 8 + j];
        ushort h, m, l;
        split3rne(g, h, m, l);
        gsp[idx]          = h;
        gsp[GN + idx]     = m;
        gsp[2 * GN + idx] = l;
    }
    const int lane = threadIdx.x & 63;
    const int j    = blockIdx.x * 4 + (threadIdx.x >> 6);
    ctx_body(j, lane, rc, ctx_w, ctx_out);
}

// ---------------------------------------------------------------------------
// Kernel 2: cl[b][e] = dot(ctx[b,:], gate_w[e,:]) — 64 blocks, tiny.
// ---------------------------------------------------------------------------
__global__ __launch_bounds__(256) void cl_kernel(
    const float* __restrict__ gw, const float* __restrict__ ctx,
    float* __restrict__ cl)
{
    const int lane = threadIdx.x & 63;
    const int pk   = blockIdx.x * 4 + (threadIdx.x >> 6);  // 0..255
    const int b    = pk >> 6;
    const int e    = pk & 63;
    const float4* wr = (const float4*)(gw + (size_t)e * C_DIM);
    const float4* cr = (const float4*)(ctx + (size_t)b * C_DIM);
    float s = 0.f;
#pragma unroll
    for (int it = 0; it < 8; ++it) {
        float4 a = wr[it * 64 + lane];
        float4 c = cr[it * 64 + lane];
        s += a.x * c.x + a.y * c.y + a.z * c.z + a.w * c.w;
    }
#pragma unroll
    for (int off = 32; off; off >>= 1) s += __shfl_xor(s, off, 64);
    if (lane == 0) cl[pk] = s;
}

// ---------------------------------------------------------------------------
// Kernel 3 (R9): K-full fused GEMM + in-register epilogue (R8 structure)
// WITH R6's LDS-B double-buffer restored.
// R8 counters (100.6us, 704 GB/s, MfmaUtil 9.8, VGPR_Count=60!) prove the
// compiler re-serialized the 12 per-step B vmem loads at L2 latency
// (64 steps x 12 x ~250cy ~= 88us = the kernel). Same mechanism as R2-R5;
// R6's LDS staging was the one change that ever helped and it fixed exactly
// this path. Restored here: B global->reg->LDS (pre-swizzled source, linear
// dest, swizzled read; proven involution), 1 barrier/step; inner loop reads
// B via ds_read_b128 (compiler-pipelined lgkmcnt). A: 4-deep register
// prefetch chain (~1800cy lead >> HBM latency). B values + MFMA order
// bit-identical to R8 (refcheck-passed) => same absmax.
// ---------------------------------------------------------------------------
__global__ __launch_bounds__(128, 1) void fused_kernel(
    const float* __restrict__ x, const ushort* __restrict__ gsp,
    const float* __restrict__ cl, float* __restrict__ out,
    float* __restrict__ bp)
{
    __shared__ ushort Bs[2][3][2048];        // 24 KB double-buffered B step
    __shared__ float  red[2][128];

    const int tid  = threadIdx.x;
    const int wv   = tid >> 6;              // 0..1
    const int lane = tid & 63;
    const int l15  = lane & 15;
    const int quad = lane >> 4;
    const int t0   = blockIdx.x * 32;       // 32 tokens per block
    const int b    = t0 >> 12;              // batch (4096 tokens each)

    floatx4 acc[4];
#pragma unroll
    for (int nt = 0; nt < 4; ++nt) acc[nt] = (floatx4){0.f, 0.f, 0.f, 0.f};

    // A stream: lane (l15,quad) reads row t0+wv*16+l15, 8 floats at quad*8,
    // advancing 32 floats per K-step.
    const float* xr = x + (size_t)(t0 + wv * 16 + l15) * C_DIM + quad * 8;

    // B staging: 128 threads x 2 slots x 3 parts. Within each 2048-ushort
    // step block, LDS[P] = G[step_base + (P ^ (((P>>9)&3)<<3))] (involution).
    const int sl0 = tid * 8;                 // slot 0 element base
    const int sl1 = (tid + 128) * 8;         // slot 1 element base
    const int sw0 = sl0 ^ (((sl0 >> 9) & 3) << 3);
    const int sw1 = sl1 ^ (((sl1 >> 9) & 3) << 3);

    // Swizzled read offsets (per-lane constants), proven R6:
    int roff[4];
#pragma unroll
    for (int nt = 0; nt < 4; ++nt)
        roff[nt] = quad * 512 + (((16 * nt + l15) ^ quad) << 3);

    // ---- prologue: B[0] regs + A[0..3] prefetch chain ----
    short8 s00 = *(const short8*)(gsp + 0 * (size_t)GN + sw0);
    short8 s01 = *(const short8*)(gsp + 0 * (size_t)GN + sw1);
    short8 s10 = *(const short8*)(gsp + 1 * (size_t)GN + sw0);
    short8 s11 = *(const short8*)(gsp + 1 * (size_t)GN + sw1);
    short8 s20 = *(const short8*)(gsp + 2 * (size_t)GN + sw0);
    short8 s21 = *(const short8*)(gsp + 2 * (size_t)GN + sw1);
    float4 pa0 = *(const float4*)(xr);       float4 pa1 = *(const float4*)(xr + 4);
    float4 pb0 = *(const float4*)(xr + 32);  float4 pb1 = *(const float4*)(xr + 36);
    float4 pc0 = *(const float4*)(xr + 64);  float4 pc1 = *(const float4*)(xr + 68);
    float4 pd0 = *(const float4*)(xr + 96);  float4 pd1 = *(const float4*)(xr + 100);

#pragma unroll 2
    for (int ks = 0; ks < 64; ++ks) {
        // --- commit staged B[ks] regs to LDS buf[ks&1] (linear dest) ---
        ushort* bw = &Bs[ks & 1][0][0];
        *(short8*)(bw + 0 * 2048 + sl0) = s00;
        *(short8*)(bw + 0 * 2048 + sl1) = s01;
        *(short8*)(bw + 1 * 2048 + sl0) = s10;
        *(short8*)(bw + 1 * 2048 + sl1) = s11;
        *(short8*)(bw + 2 * 2048 + sl0) = s20;
        *(short8*)(bw + 2 * 2048 + sl1) = s21;

        // --- issue next-step B loads (wrap on last; discarded) ---
        const int nk = (ks + 1 < 64) ? ks + 1 : 0;
        const size_t nb_ = (size_t)nk * 2048;
        s00 = *(const short8*)(gsp + 0 * (size_t)GN + nb_ + sw0);
        s01 = *(const short8*)(gsp + 0 * (size_t)GN + nb_ + sw1);
        s10 = *(const short8*)(gsp + 1 * (size_t)GN + nb_ + sw0);
        s11 = *(const short8*)(gsp + 1 * (size_t)GN + nb_ + sw1);
        s20 = *(const short8*)(gsp + 2 * (size_t)GN + nb_ + sw0);
        s21 = *(const short8*)(gsp + 2 * (size_t)GN + nb_ + sw1);

        // --- issue A[ks+4] (wrap on tail; discarded) ---
        const int fk = (ks + 4 < 64) ? ks + 4 : 0;
        float4 f0 = *(const float4*)(xr + fk * 32);
        float4 f1 = *(const float4*)(xr + fk * 32 + 4);

        // --- split current A while loads fly ---
        short8 ah, am, al;
        splitpack8(pa0, pa1, ah, am, al);

        __syncthreads();   // B[ks] LDS writes visible to both waves

        // --- inner MFMA loop: B from LDS (swizzled read) ---
        const ushort* br = &Bs[ks & 1][0][0];
#pragma unroll
        for (int nt = 0; nt < 4; ++nt) {
            short8 bh = *(const short8*)(br + 0 * 2048 + roff[nt]);
            short8 bm = *(const short8*)(br + 1 * 2048 + roff[nt]);
            short8 bl = *(const short8*)(br + 2 * 2048 + roff[nt]);
            acc[nt] = __builtin_amdgcn_mfma_f32_16x16x32_bf16(ah, bh, acc[nt], 0, 0, 0);
            acc[nt] = __builtin_amdgcn_mfma_f32_16x16x32_bf16(ah, bm, acc[nt], 0, 0, 0);
            acc[nt] = __builtin_amdgcn_mfma_f32_16x16x32_bf16(am, bh, acc[nt], 0, 0, 0);
            acc[nt] = __builtin_amdgcn_mfma_f32_16x16x32_bf16(ah, bl, acc[nt], 0, 0, 0);
            acc[nt] = __builtin_amdgcn_mfma_f32_16x16x32_bf16(al, bh, acc[nt], 0, 0, 0);
            acc[nt] = __builtin_amdgcn_mfma_f32_16x16x32_bf16(am, bm, acc[nt], 0, 0, 0);
        }
        // no end barrier: next iteration writes the OTHER buffer, whose last
        // readers passed the barrier we just crossed.

        pa0 = pb0; pa1 = pb1; pb0 = pc0; pb1 = pc1;
        pc0 = pd0; pc1 = pd1; pd0 = f0;  pd1 = f1;
    }

    // ---- fused epilogue (R8-proven) ----
    // D layout: token row = quad*4 + r, expert col = 16*nt + l15.
    float clv[4];
#pragma unroll
    for (int nt = 0; nt < 4; ++nt) clv[nt] = cl[b * 64 + 16 * nt + l15];

    float imp4[4] = {0.f, 0.f, 0.f, 0.f};
    float cnt4[4] = {0.f, 0.f, 0.f, 0.f};

#pragma unroll
    for (int r = 0; r < 4; ++r) {
        const int t = t0 + wv * 16 + quad * 4 + r;
        float v[4], p[4];
#pragma unroll
        for (int nt = 0; nt < 4; ++nt) {
            v[nt] = acc[nt][r] + clv[nt];
            p[nt] = expf(v[nt]);
        }
        float s = (p[0] + p[1]) + (p[2] + p[3]);

        // local top-2 over the lane's 4 experts (ids 16nt+l15, increasing)
        float v1 = v[0];      int i1 = l15;
        float v2 = -INFINITY; int i2 = 0x7fffffff;
#pragma unroll
        for (int k = 1; k < 4; ++k) {
            const int e = 16 * k + l15;
            if (v[k] > v1) { v2 = v1; i2 = i1; v1 = v[k]; i1 = e; }
            else if (v[k] > v2 || (v[k] == v2 && e < i2)) { v2 = v[k]; i2 = e; }
        }

        // 16-lane butterfly merge (same comparator as proven epilogue)
#pragma unroll
        for (int off = 8; off; off >>= 1) {
            float ov1 = __shfl_xor(v1, off, 64);
            int   oi1 = __shfl_xor(i1, off, 64);
            float ov2 = __shfl_xor(v2, off, 64);
            int   oi2 = __shfl_xor(i2, off, 64);
            s += __shfl_xor(s, off, 64);
            const bool aw = (ov1 < v1) || (ov1 == v1 && i1 < oi1);
            const float lv = aw ? ov1 : v1;  const int li = aw ? oi1 : i1;
            const float wv2 = aw ? v2 : ov2; const int wi = aw ? i2 : oi2;
            if (!aw) { v1 = ov1; i1 = oi1; }
            const bool sw = (wv2 < lv) || (wv2 == lv && li < wi);
            v2 = sw ? lv : wv2; i2 = sw ? li : wi;
        }

#pragma unroll
        for (int nt = 0; nt < 4; ++nt) {
            const int e = 16 * nt + l15;
            imp4[nt] += p[nt] / s;
            cnt4[nt] += ((e == i1) ? 1.f : 0.f) + ((e == i2) ? 1.f : 0.f);
        }

        if (l15 == 0) {
            const float e2 = expf(v2 - v1);
            out[2 * t]     = (float)i1;
            out[2 * t + 1] = (float)i2;
            out[2 * T_TOKENS + 2 * t]     = 1.f / (1.f + e2);
            out[2 * T_TOKENS + 2 * t + 1] = e2 / (1.f + e2);
        }
    }

    // reduce imp/cnt across the 4 quads (lanes sharing the same expert set)
#pragma unroll
    for (int nt = 0; nt < 4; ++nt) {
        imp4[nt] += __shfl_xor(imp4[nt], 16, 64);
        imp4[nt] += __shfl_xor(imp4[nt], 32, 64);
        cnt4[nt] += __shfl_xor(cnt4[nt], 16, 64);
        cnt4[nt] += __shfl_xor(cnt4[nt], 32, 64);
    }
    if (quad == 0) {
#pragma unroll
        for (int nt = 0; nt < 4; ++nt) {
            red[wv][16 * nt + l15]      = imp4[nt];
            red[wv][64 + 16 * nt + l15] = cnt4[nt];
        }
    }
    __syncthreads();
    if (tid < 128)
        bp[(size_t)blockIdx.x * 128 + tid] = red[0][tid] + red[1][tid];
}

// ---------------------------------------------------------------------------
// Kernel 4: parallel bp reduce -> aux loss (proven; nb = FBLK)
// ---------------------------------------------------------------------------
__global__ __launch_bounds__(1024) void aux_kernel(
    const float* __restrict__ bp, int nb, float* __restrict__ out_aux)
{
    __shared__ float4 red[32][32];
    const int tid = threadIdx.x;
    const int c4  = tid & 31;
    const int grp = tid >> 5;

    const float4* bp4 = (const float4*)bp;
    float4 s = make_float4(0.f, 0.f, 0.f, 0.f);
    for (int r = grp; r < nb; r += 32) {
        float4 v = bp4[(size_t)r * 32 + c4];
        s.x += v.x; s.y += v.y; s.z += v.z; s.w += v.w;
    }
    red[grp][c4] = s;
    __syncthreads();

    if (tid < 32) {
        float4 t = make_float4(0.f, 0.f, 0.f, 0.f);
#pragma unroll
        for (int g = 0; g < 32; ++g) {
            float4 v = red[g][tid];
            t.x += v.x; t.y += v.y; t.z += v.z; t.w += v.w;
        }
        red[0][tid] = t;
    }
    __syncthreads();

    if (tid < 16) {
        float4 a = red[0][tid];
        float4 b = red[0][tid + 16];
        float v = a.x * b.x + a.y * b.y + a.z * b.z + a.w * b.w;
#pragma unroll
        for (int off = 8; off; off >>= 1) v += __shfl_xor(v, off, 64);
        if (tid == 0)
            out_aux[0] = (float)E_EXP * v / ((float)T_TOKENS * (float)T_TOKENS);
    }
}

// ---------------------------------------------------------------------------
// Fallback path kernels (ws too small): fused fp32 + aux (proven)
// ---------------------------------------------------------------------------
#define TM    64
#define FKC   64
#define FLSTR 68
__global__ __launch_bounds__(256) void router_fused_kernel(
    const float* __restrict__ x, const float* __restrict__ gate_w,
    const float* __restrict__ ctx, float* __restrict__ out,
    float* __restrict__ bp)
{
    __shared__ float xs[TM][FLSTR];
    __shared__ float gs[E_EXP][FLSTR];
    __shared__ float ls[TM][FLSTR];
    __shared__ float red[4][128];

    const int tid = threadIdx.x;
    const int eg  = tid & 15;
    const int tg  = tid >> 4;
    const int t0  = blockIdx.x * TM;
    const int b   = t0 / N_SEQ;
    const int sr  = tid >> 4;
    const int scg = tid & 15;
    const float* ctx_row = ctx + (size_t)b * C_DIM;

    float4 acc[4][4];
#pragma unroll
    for (int i = 0; i < 4; ++i)
#pragma unroll
        for (int j = 0; j < 4; ++j) acc[i][j] = make_float4(0.f, 0.f, 0.f, 0.f);

    float4 px[4], pg[4], pc;
    auto prefetch = [&](int kc) {
        const int c0 = kc * FKC + scg * 4;
        pc = *(const float4*)(ctx_row + c0);
#pragma unroll
        for (int i = 0; i < 4; ++i) {
            px[i] = *(const float4*)(x + (size_t)(t0 + sr + 16 * i) * C_DIM + c0);
            pg[i] = *(const float4*)(gate_w + (size_t)(sr + 16 * i) * C_DIM + c0);
        }
    };

    prefetch(0);
    const int NCHUNK = C_DIM / FKC;
    for (int kc = 0; kc < NCHUNK; ++kc) {
        __syncthreads();
#pragma unroll
        for (int i = 0; i < 4; ++i) {
            float4 v = px[i];
            v.x += pc.x; v.y += pc.y; v.z += pc.z; v.w += pc.w;
            *(float4*)&xs[sr + 16 * i][scg * 4] = v;
            *(float4*)&gs[sr + 16 * i][scg * 4] = pg[i];
        }
        __syncthreads();
        if (kc + 1 < NCHUNK) prefetch(kc + 1);
#pragma unroll
        for (int cc = 0; cc < FKC; cc += 4) {
            float4 xv[4], gv[4];
#pragma unroll
            for (int i = 0; i < 4; ++i) xv[i] = *(const float4*)&xs[tg + 16 * i][cc];
#pragma unroll
            for (int j = 0; j < 4; ++j) gv[j] = *(const float4*)&gs[eg + 16 * j][cc];
#pragma unroll
            for (int i = 0; i < 4; ++i)
#pragma unroll
                for (int j = 0; j < 4; ++j) {
                    acc[i][j].x = fmaf(xv[i].x, gv[j].x, acc[i][j].x);
                    acc[i][j].y = fmaf(xv[i].y, gv[j].y, acc[i][j].y);
                    acc[i][j].z = fmaf(xv[i].z, gv[j].z, acc[i][j].z);
                    acc[i][j].w = fmaf(xv[i].w, gv[j].w, acc[i][j].w);
                }
        }
    }

    __syncthreads();
#pragma unroll
    for (int i = 0; i < 4; ++i)
#pragma unroll
        for (int j = 0; j < 4; ++j)
            ls[tg + 16 * i][eg + 16 * j] =
                (acc[i][j].x + acc[i][j].y) + (acc[i][j].z + acc[i][j].w);
    __syncthreads();

    const int wv   = tid >> 6;
    const int lane = tid & 63;
    float imp_acc = 0.f, cnt_acc = 0.f;

    for (int tt = 0; tt < 16; ++tt) {
        const int tokL = wv * 16 + tt;
        const float v = ls[tokL][lane];
        const float p = expf(v);
        float v1 = v;  int i1 = lane;
        float v2 = -INFINITY; int i2 = 0x7fffffff;
        float s = p;
#pragma unroll
        for (int off = 32; off; off >>= 1) {
            float ov1 = __shfl_xor(v1, off, 64);
            int   oi1 = __shfl_xor(i1, off, 64);
            float ov2 = __shfl_xor(v2, off, 64);
            int   oi2 = __shfl_xor(i2, off, 64);
            s += __shfl_xor(s, off, 64);
            const bool aw = (ov1 < v1) || (ov1 == v1 && i1 < oi1);
            const float lv = aw ? ov1 : v1;  const int li = aw ? oi1 : i1;
            const float wv2 = aw ? v2 : ov2; const int wi = aw ? i2 : oi2;
            if (!aw) { v1 = ov1; i1 = oi1; }
            const bool sw = (wv2 < lv) || (wv2 == lv && li < wi);
            v2 = sw ? lv : wv2; i2 = sw ? li : wi;
        }
        imp_acc += p / s;
        if (lane == i1 || lane == i2) cnt_acc += 1.f;
        if (lane == 0) {
            const int t = t0 + tokL;
            const float e2 = expf(v2 - v1);
            out[2 * t]     = (float)i1;
            out[2 * t + 1] = (float)i2;
            out[2 * T_TOKENS + 2 * t]     = 1.f / (1.f + e2);
            out[2 * T_TOKENS + 2 * t + 1] = e2 / (1.f + e2);
        }
    }

    red[wv][lane]      = imp_acc;
    red[wv][64 + lane] = cnt_acc;
    __syncthreads();
    if (tid < 128) {
        float s = red[0][tid] + red[1][tid] + red[2][tid] + red[3][tid];
        bp[(size_t)blockIdx.x * 128 + tid] = s;
    }
}

extern "C" void kernel_launch(void* const* d_in, const int* in_sizes, int n_in,
                              void* d_out, int out_size, void* d_ws, size_t ws_size,
                              hipStream_t stream)
{
    (void)in_sizes; (void)n_in; (void)out_size;
    const float* x      = (const float*)d_in[0];
    const float* rc     = (const float*)d_in[1];
    const float* gate_w = (const float*)d_in[2];
    const float* ctx_w  = (const float*)d_in[3];
    float* out = (float*)d_out;

    float*  ctx = (float*)d_ws;                            // 8192 f
    float*  cl  = ctx + 8192;                              // 256 f
    float*  bp  = cl + 256;                                // FBLK*128 f
    ushort* gsp = (ushort*)(bp + (size_t)FBLK * 128);      // 3*GN us

    const size_t need =
        (8192 + 256 + (size_t)FBLK * 128) * sizeof(float)
        + (size_t)3 * GN * sizeof(ushort);

    if (ws_size >= need) {
        pre_kernel<<<512, 256, 0, stream>>>(rc, ctx_w, gate_w, ctx, gsp);
        cl_kernel<<<64, 256, 0, stream>>>(gate_w, ctx, cl);
        fused_kernel<<<FBLK, 128, 0, stream>>>(x, gsp, cl, out, bp);
        aux_kernel<<<1, 1024, 0, stream>>>(bp, FBLK, out + 2 * 2 * T_TOKENS);
    } else {
        pre_kernel<<<512, 256, 0, stream>>>(rc, ctx_w, gate_w, ctx, nullptr);
        router_fused_kernel<<<256, 256, 0, stream>>>(x, gate_w, ctx, out, bp);
        aux_kernel<<<1, 1024, 0, stream>>>(bp, 256, out + 2 * 2 * T_TOKENS);
    }
}